// Round 3
// baseline (618.428 us; speedup 1.0000x reference)
//
#include <hip/hip_runtime.h>
#include <stdint.h>

#define HW 4096
#define NC 512
#define NB 4

typedef __attribute__((ext_vector_type(8))) _Float16 f16x8;
typedef __attribute__((ext_vector_type(4))) float f32x4;
typedef __attribute__((ext_vector_type(4))) unsigned short ush4;
typedef __attribute__((ext_vector_type(8))) unsigned short ush8;

typedef __attribute__((address_space(1))) const void* as1_cvp;
typedef __attribute__((address_space(3))) void* as3_vp;

__device__ __forceinline__ unsigned short f2h(float f) {
  union { _Float16 h; unsigned short u; } c;
  c.h = (_Float16)f;           // hardware v_cvt_f16_f32, RNE
  return c.u;
}

// ---------------- moments: per-(b,c) mean/rstd over 4096 spatial elems ----------
__global__ __launch_bounds__(256) void moments_k(const float* __restrict__ x,
                                                 const float* __restrict__ y,
                                                 float* __restrict__ stats) {
  int bid = blockIdx.x;          // 0..4095 : [tensor(2)][b*C+c (2048)]
  int tens = bid >> 11;
  int row = bid & 2047;
  const float* src = (tens ? y : x) + (size_t)row * HW;
  float s = 0.f, s2 = 0.f;
  for (int j = threadIdx.x; j < HW / 4; j += 256) {
    float4 v = ((const float4*)src)[j];
    s += (v.x + v.y) + (v.z + v.w);
    s2 += (v.x * v.x + v.y * v.y) + (v.z * v.z + v.w * v.w);
  }
  #pragma unroll
  for (int o = 32; o; o >>= 1) { s += __shfl_down(s, o); s2 += __shfl_down(s2, o); }
  __shared__ float rs[8];
  int w = threadIdx.x >> 6;
  if ((threadIdx.x & 63) == 0) { rs[w] = s; rs[4 + w] = s2; }
  __syncthreads();
  if (threadIdx.x == 0) {
    float S = (rs[0] + rs[1]) + (rs[2] + rs[3]);
    float S2 = (rs[4] + rs[5]) + (rs[6] + rs[7]);
    float mean = S * (1.f / HW);
    float var = S2 * (1.f / HW) - mean * mean;
    stats[tens * 4096 + row] = mean;
    stats[tens * 4096 + 2048 + row] = rsqrtf(var + 1e-5f);
  }
}

// ------------- transpose (+optional normalize) f32 [c][i] -> f16 [i][c] ---------
// mode 0: xnT from x (normalized), 1: ynT from y (normalized), 2: yT from y raw
__global__ __launch_bounds__(256) void transnorm_k(const float* __restrict__ x,
                                                   const float* __restrict__ y,
                                                   const float* __restrict__ stats,
                                                   unsigned short* __restrict__ xnT,
                                                   unsigned short* __restrict__ ynT,
                                                   unsigned short* __restrict__ yT) {
  __shared__ float tile[64][65];
  int zi = blockIdx.z;
  int b = zi / 3, mode = zi - b * 3;
  int i0 = blockIdx.x * 64, c0 = blockIdx.y * 64;
  const float* src = (mode == 0 ? x : y);
  unsigned short* dst = (mode == 0 ? xnT : (mode == 1 ? ynT : yT));
  int t = threadIdx.x;
  int c = t >> 2;                 // 0..63
  int isub = (t & 3) << 4;        // 16 i's per thread
  float mean = 0.f, rstd = 1.f;
  if (mode < 2) {
    int srow = (mode ? 4096 : 0) + b * NC + c0 + c;
    mean = stats[srow];
    rstd = stats[srow + 2048];
  }
  const float4* sp = (const float4*)(src + ((size_t)(b * NC + c0 + c)) * HW + i0 + isub);
  #pragma unroll
  for (int k = 0; k < 4; ++k) {
    float4 v = sp[k];
    int ib = isub + k * 4;
    tile[ib + 0][c] = (v.x - mean) * rstd;
    tile[ib + 1][c] = (v.y - mean) * rstd;
    tile[ib + 2][c] = (v.z - mean) * rstd;
    tile[ib + 3][c] = (v.w - mean) * rstd;
  }
  __syncthreads();
  int i = t >> 2;
  int cc = (t & 3) << 4;
  unsigned short* op = dst + ((size_t)b * HW + i0 + i) * NC + c0 + cc;
  #pragma unroll
  for (int h = 0; h < 2; ++h) {
    ush8 o;
    #pragma unroll
    for (int e = 0; e < 8; ++e) o[e] = f2h(tile[i][cc + h * 8 + e]);
    *(ush8*)(op + h * 8) = o;
  }
}

// ---------------- cast the four 512x512 weight matrices to f16 ------------------
__global__ __launch_bounds__(256) void castw_k(const float* __restrict__ fw,
                                               const float* __restrict__ gw,
                                               const float* __restrict__ hw_,
                                               const float* __restrict__ ow,
                                               unsigned short* __restrict__ dst) {
  int idx = blockIdx.x * 256 + threadIdx.x;   // float4 index, total 262144
  int which = idx >> 16;
  int sub = idx & 65535;
  const float* s = which == 0 ? fw : which == 1 ? gw : which == 2 ? hw_ : ow;
  float4 v = ((const float4*)s)[sub];
  ush4 o;
  o[0] = f2h(v.x); o[1] = f2h(v.y); o[2] = f2h(v.z); o[3] = f2h(v.w);
  *(ush4*)(dst + (size_t)idx * 4) = o;
}

// -------- row softmax over 4096 f32, write f16 IN PLACE (row pitch 8192) --------
__global__ __launch_bounds__(256) void softmax_k(float* __restrict__ S) {
  float* row = S + (size_t)blockIdx.x * HW;
  int t = threadIdx.x;
  float4 v[4];
  float mx = -3.0e38f;
  #pragma unroll
  for (int r = 0; r < 4; ++r) {
    v[r] = ((const float4*)row)[r * 256 + t];
    mx = fmaxf(mx, fmaxf(fmaxf(v[r].x, v[r].y), fmaxf(v[r].z, v[r].w)));
  }
  #pragma unroll
  for (int o = 32; o; o >>= 1) mx = fmaxf(mx, __shfl_down(mx, o));
  __shared__ float red[8];
  int w = t >> 6;
  if ((t & 63) == 0) red[w] = mx;
  __syncthreads();
  mx = fmaxf(fmaxf(red[0], red[1]), fmaxf(red[2], red[3]));
  float sum = 0.f;
  #pragma unroll
  for (int r = 0; r < 4; ++r) {
    v[r].x = __expf(v[r].x - mx);
    v[r].y = __expf(v[r].y - mx);
    v[r].z = __expf(v[r].z - mx);
    v[r].w = __expf(v[r].w - mx);
    sum += (v[r].x + v[r].y) + (v[r].z + v[r].w);
  }
  #pragma unroll
  for (int o = 32; o; o >>= 1) sum += __shfl_down(sum, o);
  if ((t & 63) == 0) red[4 + w] = sum;
  __syncthreads();
  float inv = 1.f / ((red[4] + red[5]) + (red[6] + red[7]));
  unsigned short* orow = (unsigned short*)row;
  #pragma unroll
  for (int r = 0; r < 4; ++r) {
    ush4 o;
    o[0] = f2h(v[r].x * inv);
    o[1] = f2h(v[r].y * inv);
    o[2] = f2h(v[r].z * inv);
    o[3] = f2h(v[r].w * inv);
    *(ush4*)(orow + ((size_t)(r * 256 + t)) * 4) = o;
  }
}

// ------------------- NT GEMM: C[m][n] = sum_k A[m][k]*B[n][k] -------------------
// f16 operands, 128x128 tile, BK=64, 256 thr = 4 waves (2x2), wave tile 64x64.
// LDS staged via global_load_lds(16B) with XOR source pre-swizzle (chunk^row&7).
__global__ __launch_bounds__(256) void gemm_nt(
    const unsigned short* __restrict__ A, long long sA, int lda,
    const unsigned short* __restrict__ Bm, long long sB, int ldb,
    void* __restrict__ Cp, long long sC, int ldc,
    int K, int out_f32,
    const float* __restrict__ bias_m, const float* __restrict__ bias_n,
    const float* __restrict__ add_src, long long sAdd) {
  __shared__ short lsA[128 * 64];
  __shared__ short lsB[128 * 64];
  const int t = threadIdx.x;
  const int lane = t & 63;
  const int w = t >> 6;
  const int wm = w >> 1, wn = w & 1;
  const long long bz = blockIdx.z;
  const unsigned short* Ab = A + bz * sA + (size_t)blockIdx.x * 128 * lda;
  const unsigned short* Bb = Bm + bz * sB + (size_t)blockIdx.y * 128 * ldb;

  f32x4 zero = {0.f, 0.f, 0.f, 0.f};
  f32x4 acc[4][4];
  #pragma unroll
  for (int i = 0; i < 4; ++i)
    #pragma unroll
    for (int j = 0; j < 4; ++j) acc[i][j] = zero;

  const int nkt = K >> 6;
  for (int kt = 0; kt < nkt; ++kt) {
    const int kbase = kt << 6;
    #pragma unroll
    for (int i = 0; i < 4; ++i) {
      int q = t + i * 256;               // chunk id 0..1023
      int r = q >> 3, xx = q & 7;        // row, physical 16B chunk
      int gk = kbase + ((xx ^ (r & 7)) << 3);
      __builtin_amdgcn_global_load_lds((as1_cvp)(const void*)(Ab + (size_t)r * lda + gk),
                                       (as3_vp)(void*)(&lsA[q << 3]), 16, 0, 0);
      __builtin_amdgcn_global_load_lds((as1_cvp)(const void*)(Bb + (size_t)r * ldb + gk),
                                       (as3_vp)(void*)(&lsB[q << 3]), 16, 0, 0);
    }
    __syncthreads();
    #pragma unroll
    for (int ks = 0; ks < 2; ++ks) {
      f16x8 av[4], bv[4];
      const int xl = ks * 4 + (lane >> 4);
      const int rr = lane & 15;
      #pragma unroll
      for (int mb = 0; mb < 4; ++mb) {
        int row = wm * 64 + mb * 16 + rr;
        av[mb] = *(const f16x8*)&lsA[(row << 6) + ((xl ^ (row & 7)) << 3)];
      }
      #pragma unroll
      for (int nb = 0; nb < 4; ++nb) {
        int row = wn * 64 + nb * 16 + rr;
        bv[nb] = *(const f16x8*)&lsB[(row << 6) + ((xl ^ (row & 7)) << 3)];
      }
      #pragma unroll
      for (int mb = 0; mb < 4; ++mb)
        #pragma unroll
        for (int nb = 0; nb < 4; ++nb)
          acc[mb][nb] = __builtin_amdgcn_mfma_f32_16x16x32_f16(av[mb], bv[nb], acc[mb][nb], 0, 0, 0);
    }
    __syncthreads();
  }

  const int mb0 = blockIdx.x * 128 + wm * 64;
  const int nb0 = blockIdx.y * 128 + wn * 64;
  const int cn = lane & 15;
  const int rq = (lane >> 4) << 2;
  float* cf = (float*)Cp;
  unsigned short* ch = (unsigned short*)Cp;
  #pragma unroll
  for (int mb = 0; mb < 4; ++mb) {
    #pragma unroll
    for (int nb = 0; nb < 4; ++nb) {
      int n = nb0 + nb * 16 + cn;
      float bn = bias_n ? bias_n[n] : 0.f;
      #pragma unroll
      for (int r = 0; r < 4; ++r) {
        int m = mb0 + mb * 16 + rq + r;
        float vv = acc[mb][nb][r] + bn;
        if (bias_m) vv += bias_m[m];
        if (add_src) vv += add_src[bz * sAdd + (size_t)m * ldc + n];
        size_t off = (size_t)(bz * sC) + (size_t)m * ldc + n;
        if (out_f32) cf[off] = vv;
        else ch[off] = f2h(vv);
      }
    }
  }
}

extern "C" void kernel_launch(void* const* d_in, const int* in_sizes, int n_in,
                              void* d_out, int out_size, void* d_ws, size_t ws_size,
                              hipStream_t stream) {
  const float* x = (const float*)d_in[0];
  const float* y = (const float*)d_in[1];
  const float* f_w = (const float*)d_in[2];
  const float* f_b = (const float*)d_in[3];
  const float* g_w = (const float*)d_in[4];
  const float* g_b = (const float*)d_in[5];
  const float* h_w = (const float*)d_in[6];
  const float* h_b = (const float*)d_in[7];
  const float* out_w = (const float*)d_in[8];
  const float* out_b = (const float*)d_in[9];
  float* out = (float*)d_out;

  char* ws = (char*)d_ws;
  size_t off = 0;
  auto alloc = [&](size_t bytes) -> char* {
    char* p = ws + off;
    off += (bytes + 255) & ~(size_t)255;
    return p;
  };
  const size_t TN = (size_t)NB * HW * NC;  // 8,388,608 elements per [B][HW][C] buf
  float* stats = (float*)alloc(8192 * sizeof(float));
  unsigned short* wB = (unsigned short*)alloc((size_t)4 * 512 * 512 * 2);
  unsigned short* xnT = (unsigned short*)alloc(TN * 2);
  unsigned short* ynT = (unsigned short*)alloc(TN * 2);
  unsigned short* yT = (unsigned short*)alloc(TN * 2);
  unsigned short* fB = (unsigned short*)alloc(TN * 2);
  unsigned short* gB = (unsigned short*)alloc(TN * 2);
  unsigned short* hB = (unsigned short*)alloc(TN * 2);
  unsigned short* oB = xnT;  // alias: xnT dead after f-GEMM, before first PV write
  size_t remain = ws_size > off ? ws_size - off : 0;
  const size_t S4bytes = (size_t)NB * HW * HW * 4;   // 256 MB: all-batch S
  int batched = remain >= S4bytes;
  int chunk = 4096;
  if (!batched) {
    while (chunk > 128 && (size_t)chunk * HW * 4 > remain) chunk >>= 1;
  }
  float* S = (float*)alloc(batched ? S4bytes : (size_t)chunk * HW * 4);
  if (off > ws_size) return;  // scratch too small; cannot run

  castw_k<<<dim3(1024), dim3(256), 0, stream>>>(f_w, g_w, h_w, out_w, wB);
  moments_k<<<dim3(4096), dim3(256), 0, stream>>>(x, y, stats);
  transnorm_k<<<dim3(64, 8, 12), dim3(256), 0, stream>>>(x, y, stats, xnT, ynT, yT);

  const long long PS = (long long)HW * NC;  // per-batch stride (elements)
  // f[b][i][o] = xnT · f_w^T  (bias over n=o)
  gemm_nt<<<dim3(32, 4, NB), dim3(256), 0, stream>>>(xnT, PS, NC, wB, 0, NC,
                                                     fB, PS, NC, NC, 0,
                                                     nullptr, f_b, nullptr, 0);
  // g[b][j][o] = ynT · g_w^T
  gemm_nt<<<dim3(32, 4, NB), dim3(256), 0, stream>>>(ynT, PS, NC, wB + 262144, 0, NC,
                                                     gB, PS, NC, NC, 0,
                                                     nullptr, g_b, nullptr, 0);
  // h[b][o][j] = h_w · yT^T  (bias over m=o)
  gemm_nt<<<dim3(4, 32, NB), dim3(256), 0, stream>>>(wB + 524288, 0, NC, yT, PS, NC,
                                                     hB, PS, HW, NC, 0,
                                                     h_b, nullptr, nullptr, 0);

  if (batched) {
    const long long SSf = (long long)HW * HW;        // f32 elems per batch S
    const long long SSh = (long long)HW * 2 * HW;    // f16 elems per batch S (pitch 8192)
    // S[b][i][j] = f[i][:] · g[j][:]  (f32 out)  — 4096 blocks, all batches
    gemm_nt<<<dim3(32, 32, NB), dim3(256), 0, stream>>>(
        fB, PS, NC, gB, PS, NC, S, SSf, HW, NC, 1, nullptr, nullptr, nullptr, 0);
    // row softmax over all 16384 rows, f16 in place
    softmax_k<<<dim3(NB * HW), dim3(256), 0, stream>>>(S);
    // O[b][i][c] = P[i][:] · h[c][:]  — 512 blocks = 2/CU
    gemm_nt<<<dim3(32, 4, NB), dim3(256), 0, stream>>>(
        (const unsigned short*)S, SSh, 2 * HW,
        hB, PS, HW,
        oB, PS, NC, HW, 0, nullptr, nullptr, nullptr, 0);
  } else {
    for (int b = 0; b < NB; ++b) {
      for (int r0 = 0; r0 < HW; r0 += chunk) {
        gemm_nt<<<dim3(chunk / 128, 32, 1), dim3(256), 0, stream>>>(
            fB + ((size_t)b * HW + r0) * NC, 0, NC,
            gB + (size_t)b * HW * NC, 0, NC,
            S, 0, HW, NC, 1, nullptr, nullptr, nullptr, 0);
        softmax_k<<<dim3(chunk), dim3(256), 0, stream>>>(S);
        gemm_nt<<<dim3(chunk / 128, 4, 1), dim3(256), 0, stream>>>(
            (const unsigned short*)S, 0, 2 * HW,
            hB + (size_t)b * NC * HW, 0, HW,
            oB + ((size_t)b * HW + r0) * NC, 0, NC, HW, 0,
            nullptr, nullptr, nullptr, 0);
      }
    }
  }
  // out[b][o][i] = out_w · O^T + out_b + x   (f32 out)
  gemm_nt<<<dim3(4, 32, NB), dim3(256), 0, stream>>>(wB + 786432, 0, NC, oB, PS, NC,
                                                     out, (long long)NC * HW, HW, NC, 1,
                                                     out_b, nullptr, x, (long long)NC * HW);
}

// Round 5
// 465.483 us; speedup vs baseline: 1.3286x; 1.3286x over previous
//
#include <hip/hip_runtime.h>
#include <stdint.h>

#define HW 4096
#define NC 512
#define NB 4

typedef __attribute__((ext_vector_type(8))) _Float16 f16x8;
typedef __attribute__((ext_vector_type(4))) float f32x4;
typedef __attribute__((ext_vector_type(4))) unsigned short ush4;
typedef __attribute__((ext_vector_type(8))) unsigned short ush8;

typedef __attribute__((address_space(1))) const void* as1_cvp;
typedef __attribute__((address_space(3))) void* as3_vp;

__device__ __forceinline__ unsigned short f2h(float f) {
  union { _Float16 h; unsigned short u; } c;
  c.h = (_Float16)f;           // hardware v_cvt_f16_f32, RNE
  return c.u;
}

// ---------------- moments: per-(b,c) mean/rstd over 4096 spatial elems ----------
__global__ __launch_bounds__(256) void moments_k(const float* __restrict__ x,
                                                 const float* __restrict__ y,
                                                 float* __restrict__ stats) {
  int bid = blockIdx.x;          // 0..4095 : [tensor(2)][b*C+c (2048)]
  int tens = bid >> 11;
  int row = bid & 2047;
  const float* src = (tens ? y : x) + (size_t)row * HW;
  float s = 0.f, s2 = 0.f;
  for (int j = threadIdx.x; j < HW / 4; j += 256) {
    float4 v = ((const float4*)src)[j];
    s += (v.x + v.y) + (v.z + v.w);
    s2 += (v.x * v.x + v.y * v.y) + (v.z * v.z + v.w * v.w);
  }
  #pragma unroll
  for (int o = 32; o; o >>= 1) { s += __shfl_down(s, o); s2 += __shfl_down(s2, o); }
  __shared__ float rs[8];
  int w = threadIdx.x >> 6;
  if ((threadIdx.x & 63) == 0) { rs[w] = s; rs[4 + w] = s2; }
  __syncthreads();
  if (threadIdx.x == 0) {
    float S = (rs[0] + rs[1]) + (rs[2] + rs[3]);
    float S2 = (rs[4] + rs[5]) + (rs[6] + rs[7]);
    float mean = S * (1.f / HW);
    float var = S2 * (1.f / HW) - mean * mean;
    stats[tens * 4096 + row] = mean;
    stats[tens * 4096 + 2048 + row] = rsqrtf(var + 1e-5f);
  }
}

// ------------- transpose (+optional normalize) f32 [c][i] -> f16 [i][c] ---------
// mode 0: xnT from x (normalized), 1: ynT from y (normalized), 2: yT from y raw
__global__ __launch_bounds__(256) void transnorm_k(const float* __restrict__ x,
                                                   const float* __restrict__ y,
                                                   const float* __restrict__ stats,
                                                   unsigned short* __restrict__ xnT,
                                                   unsigned short* __restrict__ ynT,
                                                   unsigned short* __restrict__ yT) {
  __shared__ float tile[64][65];
  int zi = blockIdx.z;
  int b = zi / 3, mode = zi - b * 3;
  int i0 = blockIdx.x * 64, c0 = blockIdx.y * 64;
  const float* src = (mode == 0 ? x : y);
  unsigned short* dst = (mode == 0 ? xnT : (mode == 1 ? ynT : yT));
  int t = threadIdx.x;
  int c = t >> 2;                 // 0..63
  int isub = (t & 3) << 4;        // 16 i's per thread
  float mean = 0.f, rstd = 1.f;
  if (mode < 2) {
    int srow = (mode ? 4096 : 0) + b * NC + c0 + c;
    mean = stats[srow];
    rstd = stats[srow + 2048];
  }
  const float4* sp = (const float4*)(src + ((size_t)(b * NC + c0 + c)) * HW + i0 + isub);
  #pragma unroll
  for (int k = 0; k < 4; ++k) {
    float4 v = sp[k];
    int ib = isub + k * 4;
    tile[ib + 0][c] = (v.x - mean) * rstd;
    tile[ib + 1][c] = (v.y - mean) * rstd;
    tile[ib + 2][c] = (v.z - mean) * rstd;
    tile[ib + 3][c] = (v.w - mean) * rstd;
  }
  __syncthreads();
  int i = t >> 2;
  int cc = (t & 3) << 4;
  unsigned short* op = dst + ((size_t)b * HW + i0 + i) * NC + c0 + cc;
  #pragma unroll
  for (int h = 0; h < 2; ++h) {
    ush8 o;
    #pragma unroll
    for (int e = 0; e < 8; ++e) o[e] = f2h(tile[i][cc + h * 8 + e]);
    *(ush8*)(op + h * 8) = o;
  }
}

// ---------------- cast the four 512x512 weight matrices to f16 ------------------
__global__ __launch_bounds__(256) void castw_k(const float* __restrict__ fw,
                                               const float* __restrict__ gw,
                                               const float* __restrict__ hw_,
                                               const float* __restrict__ ow,
                                               unsigned short* __restrict__ dst) {
  int idx = blockIdx.x * 256 + threadIdx.x;   // float4 index, total 262144
  int which = idx >> 16;
  int sub = idx & 65535;
  const float* s = which == 0 ? fw : which == 1 ? gw : which == 2 ? hw_ : ow;
  float4 v = ((const float4*)s)[sub];
  ush4 o;
  o[0] = f2h(v.x); o[1] = f2h(v.y); o[2] = f2h(v.z); o[3] = f2h(v.w);
  *(ush4*)(dst + (size_t)idx * 4) = o;
}

// -------- row softmax over 4096 f32, write f16 IN PLACE (row pitch 8192) --------
__global__ __launch_bounds__(256) void softmax_k(float* __restrict__ S) {
  float* row = S + (size_t)blockIdx.x * HW;
  int t = threadIdx.x;
  float4 v[4];
  float mx = -3.0e38f;
  #pragma unroll
  for (int r = 0; r < 4; ++r) {
    v[r] = ((const float4*)row)[r * 256 + t];
    mx = fmaxf(mx, fmaxf(fmaxf(v[r].x, v[r].y), fmaxf(v[r].z, v[r].w)));
  }
  #pragma unroll
  for (int o = 32; o; o >>= 1) mx = fmaxf(mx, __shfl_down(mx, o));
  __shared__ float red[8];
  int w = t >> 6;
  if ((t & 63) == 0) red[w] = mx;
  __syncthreads();
  mx = fmaxf(fmaxf(red[0], red[1]), fmaxf(red[2], red[3]));
  float sum = 0.f;
  #pragma unroll
  for (int r = 0; r < 4; ++r) {
    v[r].x = __expf(v[r].x - mx);
    v[r].y = __expf(v[r].y - mx);
    v[r].z = __expf(v[r].z - mx);
    v[r].w = __expf(v[r].w - mx);
    sum += (v[r].x + v[r].y) + (v[r].z + v[r].w);
  }
  #pragma unroll
  for (int o = 32; o; o >>= 1) sum += __shfl_down(sum, o);
  if ((t & 63) == 0) red[4 + w] = sum;
  __syncthreads();
  float inv = 1.f / ((red[4] + red[5]) + (red[6] + red[7]));
  unsigned short* orow = (unsigned short*)row;
  #pragma unroll
  for (int r = 0; r < 4; ++r) {
    ush4 o;
    o[0] = f2h(v[r].x * inv);
    o[1] = f2h(v[r].y * inv);
    o[2] = f2h(v[r].z * inv);
    o[3] = f2h(v[r].w * inv);
    *(ush4*)(orow + ((size_t)(r * 256 + t)) * 4) = o;
  }
}

// ------- split-K reduce: partials live in row tails of S (2048 f32 per row) -----
// O[bg][m][c] = sum_sp S[bg*R*HW + m*HW + 2048 + sp*512 + c]
__global__ __launch_bounds__(256) void reduce_k(const float* __restrict__ S,
                                                unsigned short* __restrict__ op,
                                                long long PSo, int nsplit, int R, int pzs) {
  int e = blockIdx.x * 256 + threadIdx.x;   // float4 output index over [G][R][NC/4]
  int bg = e >> pzs;
  int rem = e - (bg << pzs);
  int m = rem >> 7;                          // NC/4 = 128
  int c4 = rem & 127;
  const float* rowp = S + (size_t)bg * R * HW + (size_t)m * HW + 2048 + c4 * 4;
  float4 s = {0.f, 0.f, 0.f, 0.f};
  for (int sp = 0; sp < nsplit; ++sp) {
    float4 v = *(const float4*)(rowp + sp * 512);
    s.x += v.x; s.y += v.y; s.z += v.z; s.w += v.w;
  }
  ush4 o;
  o[0] = f2h(s.x); o[1] = f2h(s.y); o[2] = f2h(s.z); o[3] = f2h(s.w);
  *(ush4*)(op + (size_t)bg * PSo + (size_t)m * NC + c4 * 4) = o;
}

// ------------------- NT GEMM: C[m][n] = sum_k A[m][k]*B[n][k] -------------------
// f16 operands, 128x128 tile, BK=64, 256 thr = 4 waves (2x2), wave tile 64x64.
// LDS staged via global_load_lds(16B) with XOR source pre-swizzle (chunk^row&7).
// Split-K: blockIdx.z = bg*2^ls + sp; A,B advance by sp*K along k;
// C addressed as bg*sC + sp*sCs + m*ldc + n.
__global__ __launch_bounds__(256) void gemm_nt(
    const unsigned short* __restrict__ A, long long sA, int lda,
    const unsigned short* __restrict__ Bm, long long sB, int ldb,
    void* __restrict__ Cp, long long sC, long long sCs, int ldc,
    int K, int out_f32, int ls,
    const float* __restrict__ bias_m, const float* __restrict__ bias_n,
    const float* __restrict__ add_src, long long sAdd) {
  __shared__ short lsA[128 * 64];
  __shared__ short lsB[128 * 64];
  const int t = threadIdx.x;
  const int lane = t & 63;
  const int w = t >> 6;
  const int wm = w >> 1, wn = w & 1;
  const long long bz = blockIdx.z;
  const long long bg = bz >> ls;
  const int sp = (int)(bz - (bg << ls));
  const long long koff = (long long)sp * K;
  const unsigned short* Ab = A + bg * sA + koff + (size_t)blockIdx.x * 128 * lda;
  const unsigned short* Bb = Bm + bg * sB + koff + (size_t)blockIdx.y * 128 * ldb;

  f32x4 zero = {0.f, 0.f, 0.f, 0.f};
  f32x4 acc[4][4];
  #pragma unroll
  for (int i = 0; i < 4; ++i)
    #pragma unroll
    for (int j = 0; j < 4; ++j) acc[i][j] = zero;

  const int nkt = K >> 6;
  for (int kt = 0; kt < nkt; ++kt) {
    const int kbase = kt << 6;
    #pragma unroll
    for (int i = 0; i < 4; ++i) {
      int q = t + i * 256;               // chunk id 0..1023
      int r = q >> 3, xx = q & 7;        // row, physical 16B chunk
      int gk = kbase + ((xx ^ (r & 7)) << 3);
      __builtin_amdgcn_global_load_lds((as1_cvp)(const void*)(Ab + (size_t)r * lda + gk),
                                       (as3_vp)(void*)(&lsA[q << 3]), 16, 0, 0);
      __builtin_amdgcn_global_load_lds((as1_cvp)(const void*)(Bb + (size_t)r * ldb + gk),
                                       (as3_vp)(void*)(&lsB[q << 3]), 16, 0, 0);
    }
    __syncthreads();
    #pragma unroll
    for (int ks = 0; ks < 2; ++ks) {
      f16x8 av[4], bv[4];
      const int xl = ks * 4 + (lane >> 4);
      const int rr = lane & 15;
      #pragma unroll
      for (int mb = 0; mb < 4; ++mb) {
        int row = wm * 64 + mb * 16 + rr;
        av[mb] = *(const f16x8*)&lsA[(row << 6) + ((xl ^ (row & 7)) << 3)];
      }
      #pragma unroll
      for (int nb = 0; nb < 4; ++nb) {
        int row = wn * 64 + nb * 16 + rr;
        bv[nb] = *(const f16x8*)&lsB[(row << 6) + ((xl ^ (row & 7)) << 3)];
      }
      #pragma unroll
      for (int mb = 0; mb < 4; ++mb)
        #pragma unroll
        for (int nb = 0; nb < 4; ++nb)
          acc[mb][nb] = __builtin_amdgcn_mfma_f32_16x16x32_f16(av[mb], bv[nb], acc[mb][nb], 0, 0, 0);
    }
    __syncthreads();
  }

  const int mb0 = blockIdx.x * 128 + wm * 64;
  const int nb0 = blockIdx.y * 128 + wn * 64;
  const int cn = lane & 15;
  const int rq = (lane >> 4) << 2;
  float* cf = (float*)Cp;
  unsigned short* ch = (unsigned short*)Cp;
  #pragma unroll
  for (int mb = 0; mb < 4; ++mb) {
    #pragma unroll
    for (int nb = 0; nb < 4; ++nb) {
      int n = nb0 + nb * 16 + cn;
      float bn = bias_n ? bias_n[n] : 0.f;
      #pragma unroll
      for (int r = 0; r < 4; ++r) {
        int m = mb0 + mb * 16 + rq + r;
        float vv = acc[mb][nb][r] + bn;
        if (bias_m) vv += bias_m[m];
        if (add_src) vv += add_src[bg * sAdd + (size_t)m * ldc + n];
        size_t off = (size_t)(bg * sC) + (size_t)sp * sCs + (size_t)m * ldc + n;
        if (out_f32) cf[off] = vv;
        else ch[off] = f2h(vv);
      }
    }
  }
}

extern "C" void kernel_launch(void* const* d_in, const int* in_sizes, int n_in,
                              void* d_out, int out_size, void* d_ws, size_t ws_size,
                              hipStream_t stream) {
  const float* x = (const float*)d_in[0];
  const float* y = (const float*)d_in[1];
  const float* f_w = (const float*)d_in[2];
  const float* f_b = (const float*)d_in[3];
  const float* g_w = (const float*)d_in[4];
  const float* g_b = (const float*)d_in[5];
  const float* h_w = (const float*)d_in[6];
  const float* h_b = (const float*)d_in[7];
  const float* out_w = (const float*)d_in[8];
  const float* out_b = (const float*)d_in[9];
  float* out = (float*)d_out;

  char* ws = (char*)d_ws;
  size_t off = 0;
  auto alloc = [&](size_t bytes) -> char* {
    char* p = ws + off;
    off += (bytes + 255) & ~(size_t)255;
    return p;
  };
  const size_t TN = (size_t)NB * HW * NC;  // 8,388,608 elements per [B][HW][C] buf
  float* stats = (float*)alloc(8192 * sizeof(float));
  unsigned short* wB = (unsigned short*)alloc((size_t)4 * 512 * 512 * 2);
  unsigned short* xnT = (unsigned short*)alloc(TN * 2);
  unsigned short* ynT = (unsigned short*)alloc(TN * 2);
  unsigned short* yT = (unsigned short*)alloc(TN * 2);
  unsigned short* fB = (unsigned short*)alloc(TN * 2);
  unsigned short* gB = (unsigned short*)alloc(TN * 2);
  unsigned short* hB = (unsigned short*)alloc(TN * 2);
  unsigned short* oB = xnT;      // alias: xnT dead after f-GEMM
  size_t remain = ws_size > off ? ws_size - off : 0;
  const size_t SB = (size_t)HW * HW * 4;   // 64MB: one batch's S (f32)
  int G, nsplit, R = HW;
  if (remain >= 4 * SB)      { G = 4; nsplit = 1; }
  else if (remain >= 2 * SB) { G = 2; nsplit = 2; }
  else if (remain >= SB)     { G = 1; nsplit = 4; }
  else {
    G = 1; nsplit = 4;
    while (R > 128 && (size_t)R * HW * 4 > remain) R >>= 1;
  }
  const int lsplit = (nsplit == 4) ? 2 : (nsplit == 2 ? 1 : 0);
  float* S = (float*)alloc((size_t)G * R * HW * 4);
  if (off > ws_size) return;  // scratch too small; cannot run

  castw_k<<<dim3(1024), dim3(256), 0, stream>>>(f_w, g_w, h_w, out_w, wB);
  moments_k<<<dim3(4096), dim3(256), 0, stream>>>(x, y, stats);
  transnorm_k<<<dim3(64, 8, 12), dim3(256), 0, stream>>>(x, y, stats, xnT, ynT, yT);

  const long long PS = (long long)HW * NC;  // per-batch stride (elements)
  // f[b][i][o] = xnT · f_w^T  (bias over n=o)
  gemm_nt<<<dim3(32, 4, NB), dim3(256), 0, stream>>>(xnT, PS, NC, wB, 0, NC,
                                                     fB, PS, 0, NC, NC, 0, 0,
                                                     nullptr, f_b, nullptr, 0);
  // g[b][j][o] = ynT · g_w^T
  gemm_nt<<<dim3(32, 4, NB), dim3(256), 0, stream>>>(ynT, PS, NC, wB + 262144, 0, NC,
                                                     gB, PS, 0, NC, NC, 0, 0,
                                                     nullptr, g_b, nullptr, 0);
  // h[b][o][j] = h_w · yT^T  (bias over m=o)
  gemm_nt<<<dim3(4, 32, NB), dim3(256), 0, stream>>>(wB + 524288, 0, NC, yT, PS, NC,
                                                     hB, PS, 0, HW, NC, 0, 0,
                                                     h_b, nullptr, nullptr, 0);

  const int Ksplit = HW / nsplit;
  const int pzs = 31 - __builtin_clz((unsigned)(R * (NC / 4)));  // log2 f32x4 per bg
  for (int b0 = 0; b0 < NB; b0 += G) {
    for (int r0 = 0; r0 < HW; r0 += R) {
      // S[bg][i][j] = f[i][:] · g[j][:]  (f32 out)
      gemm_nt<<<dim3(R / 128, 32, G), dim3(256), 0, stream>>>(
          fB + ((size_t)b0 * HW + r0) * NC, PS, NC,
          gB + (size_t)b0 * PS, PS, NC,
          S, (long long)R * HW, 0, HW, NC, 1, 0, nullptr, nullptr, nullptr, 0);
      // row softmax, f16 in place (pitch 8192); upper 8KB of each row now dead
      softmax_k<<<dim3(G * R), dim3(256), 0, stream>>>(S);
      // O[bg][i][c] = P[i][:] · h[c][:]  — split-K partials into S row tails
      if (nsplit > 1) {
        gemm_nt<<<dim3(R / 128, 4, G * nsplit), dim3(256), 0, stream>>>(
            (const unsigned short*)S, (long long)R * 2 * HW, 2 * HW,
            hB + (size_t)b0 * NC * HW, (long long)NC * HW, HW,
            S + 2048, (long long)R * HW, 512, HW, Ksplit, 1, lsplit,
            nullptr, nullptr, nullptr, 0);
        reduce_k<<<dim3(G * R / 2), dim3(256), 0, stream>>>(
            S, oB + ((size_t)b0 * HW + r0) * NC, PS, nsplit, R, pzs);
      } else {
        gemm_nt<<<dim3(R / 128, 4, G), dim3(256), 0, stream>>>(
            (const unsigned short*)S, (long long)R * 2 * HW, 2 * HW,
            hB + (size_t)b0 * NC * HW, (long long)NC * HW, HW,
            oB + ((size_t)b0 * HW + r0) * NC, PS, 0, NC, HW, 0, 0,
            nullptr, nullptr, nullptr, 0);
      }
    }
  }
  // out[b][o][i] = out_w · O^T + out_b + x   (f32 out)
  gemm_nt<<<dim3(4, 32, NB), dim3(256), 0, stream>>>(wB + 786432, 0, NC, oB, PS, NC,
                                                     out, (long long)NC * HW, 0, HW, NC, 1, 0,
                                                     out_b, nullptr, x, (long long)NC * HW);
}

// Round 6
// 446.482 us; speedup vs baseline: 1.3851x; 1.0426x over previous
//
#include <hip/hip_runtime.h>
#include <stdint.h>

#define HW 4096
#define NC 512
#define NB 4

typedef __attribute__((ext_vector_type(8))) _Float16 f16x8;
typedef __attribute__((ext_vector_type(4))) float f32x4;
typedef __attribute__((ext_vector_type(4))) unsigned short ush4;
typedef __attribute__((ext_vector_type(8))) unsigned short ush8;

typedef __attribute__((address_space(1))) const void* as1_cvp;
typedef __attribute__((address_space(3))) void* as3_vp;

__device__ __forceinline__ unsigned short f2h(float f) {
  union { _Float16 h; unsigned short u; } c;
  c.h = (_Float16)f;           // hardware v_cvt_f16_f32, RNE
  return c.u;
}

// ---------------- moments: per-(b,c) mean/rstd over 4096 spatial elems ----------
__global__ __launch_bounds__(256) void moments_k(const float* __restrict__ x,
                                                 const float* __restrict__ y,
                                                 float* __restrict__ stats) {
  int bid = blockIdx.x;          // 0..4095 : [tensor(2)][b*C+c (2048)]
  int tens = bid >> 11;
  int row = bid & 2047;
  const float* src = (tens ? y : x) + (size_t)row * HW;
  float s = 0.f, s2 = 0.f;
  for (int j = threadIdx.x; j < HW / 4; j += 256) {
    float4 v = ((const float4*)src)[j];
    s += (v.x + v.y) + (v.z + v.w);
    s2 += (v.x * v.x + v.y * v.y) + (v.z * v.z + v.w * v.w);
  }
  #pragma unroll
  for (int o = 32; o; o >>= 1) { s += __shfl_down(s, o); s2 += __shfl_down(s2, o); }
  __shared__ float rs[8];
  int w = threadIdx.x >> 6;
  if ((threadIdx.x & 63) == 0) { rs[w] = s; rs[4 + w] = s2; }
  __syncthreads();
  if (threadIdx.x == 0) {
    float S = (rs[0] + rs[1]) + (rs[2] + rs[3]);
    float S2 = (rs[4] + rs[5]) + (rs[6] + rs[7]);
    float mean = S * (1.f / HW);
    float var = S2 * (1.f / HW) - mean * mean;
    stats[tens * 4096 + row] = mean;
    stats[tens * 4096 + 2048 + row] = rsqrtf(var + 1e-5f);
  }
}

// ------------- transpose (+optional normalize) f32 [c][i] -> f16 [i][c] ---------
// mode 0: xnT from x (normalized), 1: ynT from y (normalized), 2: yT from y raw
__global__ __launch_bounds__(256) void transnorm_k(const float* __restrict__ x,
                                                   const float* __restrict__ y,
                                                   const float* __restrict__ stats,
                                                   unsigned short* __restrict__ xnT,
                                                   unsigned short* __restrict__ ynT,
                                                   unsigned short* __restrict__ yT) {
  __shared__ float tile[64][65];
  int zi = blockIdx.z;
  int b = zi / 3, mode = zi - b * 3;
  int i0 = blockIdx.x * 64, c0 = blockIdx.y * 64;
  const float* src = (mode == 0 ? x : y);
  unsigned short* dst = (mode == 0 ? xnT : (mode == 1 ? ynT : yT));
  int t = threadIdx.x;
  int c = t >> 2;                 // 0..63
  int isub = (t & 3) << 4;        // 16 i's per thread
  float mean = 0.f, rstd = 1.f;
  if (mode < 2) {
    int srow = (mode ? 4096 : 0) + b * NC + c0 + c;
    mean = stats[srow];
    rstd = stats[srow + 2048];
  }
  const float4* sp = (const float4*)(src + ((size_t)(b * NC + c0 + c)) * HW + i0 + isub);
  #pragma unroll
  for (int k = 0; k < 4; ++k) {
    float4 v = sp[k];
    int ib = isub + k * 4;
    tile[ib + 0][c] = (v.x - mean) * rstd;
    tile[ib + 1][c] = (v.y - mean) * rstd;
    tile[ib + 2][c] = (v.z - mean) * rstd;
    tile[ib + 3][c] = (v.w - mean) * rstd;
  }
  __syncthreads();
  int i = t >> 2;
  int cc = (t & 3) << 4;
  unsigned short* op = dst + ((size_t)b * HW + i0 + i) * NC + c0 + cc;
  #pragma unroll
  for (int h = 0; h < 2; ++h) {
    ush8 o;
    #pragma unroll
    for (int e = 0; e < 8; ++e) o[e] = f2h(tile[i][cc + h * 8 + e]);
    *(ush8*)(op + h * 8) = o;
  }
}

// ---------------- cast the four 512x512 weight matrices to f16 ------------------
__global__ __launch_bounds__(256) void castw_k(const float* __restrict__ fw,
                                               const float* __restrict__ gw,
                                               const float* __restrict__ hw_,
                                               const float* __restrict__ ow,
                                               unsigned short* __restrict__ dst) {
  int idx = blockIdx.x * 256 + threadIdx.x;   // float4 index, total 262144
  int which = idx >> 16;
  int sub = idx & 65535;
  const float* s = which == 0 ? fw : which == 1 ? gw : which == 2 ? hw_ : ow;
  float4 v = ((const float4*)s)[sub];
  ush4 o;
  o[0] = f2h(v.x); o[1] = f2h(v.y); o[2] = f2h(v.z); o[3] = f2h(v.w);
  *(ush4*)(dst + (size_t)idx * 4) = o;
}

// -------- row softmax over 4096 f32, write f16 IN PLACE (row pitch 8192) --------
__global__ __launch_bounds__(256) void softmax_k(float* __restrict__ S) {
  float* row = S + (size_t)blockIdx.x * HW;
  int t = threadIdx.x;
  float4 v[4];
  float mx = -3.0e38f;
  #pragma unroll
  for (int r = 0; r < 4; ++r) {
    v[r] = ((const float4*)row)[r * 256 + t];
    mx = fmaxf(mx, fmaxf(fmaxf(v[r].x, v[r].y), fmaxf(v[r].z, v[r].w)));
  }
  #pragma unroll
  for (int o = 32; o; o >>= 1) mx = fmaxf(mx, __shfl_down(mx, o));
  __shared__ float red[8];
  int w = t >> 6;
  if ((t & 63) == 0) red[w] = mx;
  __syncthreads();
  mx = fmaxf(fmaxf(red[0], red[1]), fmaxf(red[2], red[3]));
  float sum = 0.f;
  #pragma unroll
  for (int r = 0; r < 4; ++r) {
    v[r].x = __expf(v[r].x - mx);
    v[r].y = __expf(v[r].y - mx);
    v[r].z = __expf(v[r].z - mx);
    v[r].w = __expf(v[r].w - mx);
    sum += (v[r].x + v[r].y) + (v[r].z + v[r].w);
  }
  #pragma unroll
  for (int o = 32; o; o >>= 1) sum += __shfl_down(sum, o);
  if ((t & 63) == 0) red[4 + w] = sum;
  __syncthreads();
  float inv = 1.f / ((red[4] + red[5]) + (red[6] + red[7]));
  unsigned short* orow = (unsigned short*)row;
  #pragma unroll
  for (int r = 0; r < 4; ++r) {
    ush4 o;
    o[0] = f2h(v[r].x * inv);
    o[1] = f2h(v[r].y * inv);
    o[2] = f2h(v[r].z * inv);
    o[3] = f2h(v[r].w * inv);
    *(ush4*)(orow + ((size_t)(r * 256 + t)) * 4) = o;
  }
}

// ------- split-K reduce: partials live in row tails of S (2048 f32 per row) -----
// O[bg][m][c] = sum_sp S[bg*R*HW + m*HW + 2048 + sp*512 + c]
__global__ __launch_bounds__(256) void reduce_k(const float* __restrict__ S,
                                                unsigned short* __restrict__ op,
                                                long long PSo, int nsplit, int R, int pzs) {
  int e = blockIdx.x * 256 + threadIdx.x;   // float4 output index over [G][R][NC/4]
  int bg = e >> pzs;
  int rem = e - (bg << pzs);
  int m = rem >> 7;                          // NC/4 = 128
  int c4 = rem & 127;
  const float* rowp = S + (size_t)bg * R * HW + (size_t)m * HW + 2048 + c4 * 4;
  float4 s = {0.f, 0.f, 0.f, 0.f};
  for (int sp = 0; sp < nsplit; ++sp) {
    float4 v = *(const float4*)(rowp + sp * 512);
    s.x += v.x; s.y += v.y; s.z += v.z; s.w += v.w;
  }
  ush4 o;
  o[0] = f2h(s.x); o[1] = f2h(s.y); o[2] = f2h(s.z); o[3] = f2h(s.w);
  *(ush4*)(op + (size_t)bg * PSo + (size_t)m * NC + c4 * 4) = o;
}

// ------------------- NT GEMM (128x128, 1-phase): small matrices -----------------
__global__ __launch_bounds__(256) void gemm_nt(
    const unsigned short* __restrict__ A, long long sA, int lda,
    const unsigned short* __restrict__ Bm, long long sB, int ldb,
    void* __restrict__ Cp, long long sC, long long sCs, int ldc,
    int K, int out_f32, int ls,
    const float* __restrict__ bias_m, const float* __restrict__ bias_n,
    const float* __restrict__ add_src, long long sAdd) {
  __shared__ short lsA[128 * 64];
  __shared__ short lsB[128 * 64];
  const int t = threadIdx.x;
  const int lane = t & 63;
  const int w = t >> 6;
  const int wm = w >> 1, wn = w & 1;
  const long long bz = blockIdx.z;
  const long long bg = bz >> ls;
  const int sp = (int)(bz - (bg << ls));
  const long long koff = (long long)sp * K;
  const unsigned short* Ab = A + bg * sA + koff + (size_t)blockIdx.x * 128 * lda;
  const unsigned short* Bb = Bm + bg * sB + koff + (size_t)blockIdx.y * 128 * ldb;

  f32x4 zero = {0.f, 0.f, 0.f, 0.f};
  f32x4 acc[4][4];
  #pragma unroll
  for (int i = 0; i < 4; ++i)
    #pragma unroll
    for (int j = 0; j < 4; ++j) acc[i][j] = zero;

  const int nkt = K >> 6;
  for (int kt = 0; kt < nkt; ++kt) {
    const int kbase = kt << 6;
    #pragma unroll
    for (int i = 0; i < 4; ++i) {
      int q = t + i * 256;               // chunk id 0..1023
      int r = q >> 3, xx = q & 7;        // row, physical 16B chunk
      int gk = kbase + ((xx ^ (r & 7)) << 3);
      __builtin_amdgcn_global_load_lds((as1_cvp)(const void*)(Ab + (size_t)r * lda + gk),
                                       (as3_vp)(void*)(&lsA[q << 3]), 16, 0, 0);
      __builtin_amdgcn_global_load_lds((as1_cvp)(const void*)(Bb + (size_t)r * ldb + gk),
                                       (as3_vp)(void*)(&lsB[q << 3]), 16, 0, 0);
    }
    __syncthreads();
    #pragma unroll
    for (int ks = 0; ks < 2; ++ks) {
      f16x8 av[4], bv[4];
      const int xl = ks * 4 + (lane >> 4);
      const int rr = lane & 15;
      #pragma unroll
      for (int mb = 0; mb < 4; ++mb) {
        int row = wm * 64 + mb * 16 + rr;
        av[mb] = *(const f16x8*)&lsA[(row << 6) + ((xl ^ (row & 7)) << 3)];
      }
      #pragma unroll
      for (int nb = 0; nb < 4; ++nb) {
        int row = wn * 64 + nb * 16 + rr;
        bv[nb] = *(const f16x8*)&lsB[(row << 6) + ((xl ^ (row & 7)) << 3)];
      }
      #pragma unroll
      for (int mb = 0; mb < 4; ++mb)
        #pragma unroll
        for (int nb = 0; nb < 4; ++nb)
          acc[mb][nb] = __builtin_amdgcn_mfma_f32_16x16x32_f16(av[mb], bv[nb], acc[mb][nb], 0, 0, 0);
    }
    __syncthreads();
  }

  const int mb0 = blockIdx.x * 128 + wm * 64;
  const int nb0 = blockIdx.y * 128 + wn * 64;
  const int cn = lane & 15;
  const int rq = (lane >> 4) << 2;
  float* cf = (float*)Cp;
  unsigned short* ch = (unsigned short*)Cp;
  #pragma unroll
  for (int mb = 0; mb < 4; ++mb) {
    #pragma unroll
    for (int nb = 0; nb < 4; ++nb) {
      int n = nb0 + nb * 16 + cn;
      float bn = bias_n ? bias_n[n] : 0.f;
      #pragma unroll
      for (int r = 0; r < 4; ++r) {
        int m = mb0 + mb * 16 + rq + r;
        float vv = acc[mb][nb][r] + bn;
        if (bias_m) vv += bias_m[m];
        if (add_src) vv += add_src[bg * sAdd + (size_t)m * ldc + n];
        size_t off = (size_t)(bg * sC) + (size_t)sp * sCs + (size_t)m * ldc + n;
        if (out_f32) cf[off] = vv;
        else ch[off] = f2h(vv);
      }
    }
  }
}

// --------- NT GEMM2: 256x256 tile, BK=64, 512 thr = 8 waves (2Mx4N), ------------
// explicit LDS double-buffer + 2-phase pipeline (stage(t+1) || compute(t)),
// setprio around MFMA cluster. Same XOR chunk swizzle as gemm_nt.
__global__ __launch_bounds__(512, 2) void gemm_nt2(
    const unsigned short* __restrict__ A, long long sA, int lda,
    const unsigned short* __restrict__ Bm, long long sB, int ldb,
    void* __restrict__ Cp, long long sC, long long sCs, int ldc,
    int K, int out_f32, int ls,
    const float* __restrict__ bias_n) {
  __shared__ short lsA[2][256 * 64];
  __shared__ short lsB[2][256 * 64];
  const int t = threadIdx.x;
  const int lane = t & 63;
  const int w = t >> 6;          // 0..7
  const int wm = w >> 2, wn = w & 3;
  const long long bz = blockIdx.z;
  const long long bg = bz >> ls;
  const int sp = (int)(bz - (bg << ls));
  const long long koff = (long long)sp * K;
  const unsigned short* Ab = A + bg * sA + koff + (size_t)blockIdx.x * 256 * lda;
  const unsigned short* Bb = Bm + bg * sB + koff + (size_t)blockIdx.y * 256 * ldb;

  f32x4 zero = {0.f, 0.f, 0.f, 0.f};
  f32x4 acc[8][4];
  #pragma unroll
  for (int i = 0; i < 8; ++i)
    #pragma unroll
    for (int j = 0; j < 4; ++j) acc[i][j] = zero;

  const int rr = lane & 15;
  const int xl = lane >> 4;
  const int nkt = K >> 6;

  // stage one K-tile (A: 256x64, B: 256x64) into buffer `buf`; 8 gloads/thread
  auto STAGE = [&](int buf, int kt) {
    const int kbase = kt << 6;
    #pragma unroll
    for (int i = 0; i < 4; ++i) {
      int q = t + i * 512;               // chunk id 0..2047
      int r = q >> 3, xx = q & 7;
      int gk = kbase + ((xx ^ (r & 7)) << 3);
      __builtin_amdgcn_global_load_lds((as1_cvp)(const void*)(Ab + (size_t)r * lda + gk),
                                       (as3_vp)(void*)(&lsA[buf][q << 3]), 16, 0, 0);
      __builtin_amdgcn_global_load_lds((as1_cvp)(const void*)(Bb + (size_t)r * ldb + gk),
                                       (as3_vp)(void*)(&lsB[buf][q << 3]), 16, 0, 0);
    }
  };

  STAGE(0, 0);
  __syncthreads();                        // vmcnt(0) drain + barrier
  int cur = 0;
  for (int kt = 0; kt < nkt; ++kt) {
    if (kt + 1 < nkt) STAGE(cur ^ 1, kt + 1);   // prefetch overlaps compute
    #pragma unroll
    for (int ks = 0; ks < 2; ++ks) {
      f16x8 av[8], bv[4];
      const int cb = ks * 4 + xl;
      #pragma unroll
      for (int mb = 0; mb < 8; ++mb) {
        int row = wm * 128 + mb * 16 + rr;
        av[mb] = *(const f16x8*)&lsA[cur][(row << 6) + ((cb ^ (row & 7)) << 3)];
      }
      #pragma unroll
      for (int nb = 0; nb < 4; ++nb) {
        int row = wn * 64 + nb * 16 + rr;
        bv[nb] = *(const f16x8*)&lsB[cur][(row << 6) + ((cb ^ (row & 7)) << 3)];
      }
      __builtin_amdgcn_s_setprio(1);
      #pragma unroll
      for (int mb = 0; mb < 8; ++mb)
        #pragma unroll
        for (int nb = 0; nb < 4; ++nb)
          acc[mb][nb] = __builtin_amdgcn_mfma_f32_16x16x32_f16(av[mb], bv[nb], acc[mb][nb], 0, 0, 0);
      __builtin_amdgcn_s_setprio(0);
    }
    __syncthreads();                      // waits ds_reads + prefetch, then barrier
    cur ^= 1;
  }

  const int mb0 = blockIdx.x * 256 + wm * 128;
  const int nb0 = blockIdx.y * 256 + wn * 64;
  const int cn = lane & 15;
  const int rq = (lane >> 4) << 2;
  float* cf = (float*)Cp;
  unsigned short* ch = (unsigned short*)Cp;
  #pragma unroll
  for (int mb = 0; mb < 8; ++mb) {
    #pragma unroll
    for (int nb = 0; nb < 4; ++nb) {
      int n = nb0 + nb * 16 + cn;
      float bn = bias_n ? bias_n[n] : 0.f;
      #pragma unroll
      for (int r = 0; r < 4; ++r) {
        int m = mb0 + mb * 16 + rq + r;
        float vv = acc[mb][nb][r] + bn;
        size_t off = (size_t)(bg * sC) + (size_t)sp * sCs + (size_t)m * ldc + n;
        if (out_f32) cf[off] = vv;
        else ch[off] = f2h(vv);
      }
    }
  }
}

extern "C" void kernel_launch(void* const* d_in, const int* in_sizes, int n_in,
                              void* d_out, int out_size, void* d_ws, size_t ws_size,
                              hipStream_t stream) {
  const float* x = (const float*)d_in[0];
  const float* y = (const float*)d_in[1];
  const float* f_w = (const float*)d_in[2];
  const float* f_b = (const float*)d_in[3];
  const float* g_w = (const float*)d_in[4];
  const float* g_b = (const float*)d_in[5];
  const float* h_w = (const float*)d_in[6];
  const float* h_b = (const float*)d_in[7];
  const float* out_w = (const float*)d_in[8];
  const float* out_b = (const float*)d_in[9];
  float* out = (float*)d_out;

  char* ws = (char*)d_ws;
  size_t off = 0;
  auto alloc = [&](size_t bytes) -> char* {
    char* p = ws + off;
    off += (bytes + 255) & ~(size_t)255;
    return p;
  };
  const size_t TN = (size_t)NB * HW * NC;  // 8,388,608 elements per [B][HW][C] buf
  float* stats = (float*)alloc(8192 * sizeof(float));
  unsigned short* wB = (unsigned short*)alloc((size_t)4 * 512 * 512 * 2);
  unsigned short* xnT = (unsigned short*)alloc(TN * 2);
  unsigned short* ynT = (unsigned short*)alloc(TN * 2);
  unsigned short* yT = (unsigned short*)alloc(TN * 2);
  unsigned short* fB = (unsigned short*)alloc(TN * 2);
  unsigned short* gB = (unsigned short*)alloc(TN * 2);
  unsigned short* hB = (unsigned short*)alloc(TN * 2);
  unsigned short* oB = xnT;      // alias: xnT dead after f-GEMM
  size_t remain = ws_size > off ? ws_size - off : 0;
  const size_t SB = (size_t)HW * HW * 4;   // 64MB: one batch's S (f32)
  int G, R = HW;
  if (remain >= 4 * SB)      { G = 4; }
  else if (remain >= 2 * SB) { G = 2; }    // expected path
  else if (remain >= SB)     { G = 1; }
  else {
    G = 1;
    while (R > 128 && (size_t)R * HW * 4 > remain) R >>= 1;
  }
  float* S = (float*)alloc((size_t)G * R * HW * 4);
  if (off > ws_size) return;  // scratch too small; cannot run

  castw_k<<<dim3(1024), dim3(256), 0, stream>>>(f_w, g_w, h_w, out_w, wB);
  moments_k<<<dim3(4096), dim3(256), 0, stream>>>(x, y, stats);
  transnorm_k<<<dim3(64, 8, 12), dim3(256), 0, stream>>>(x, y, stats, xnT, ynT, yT);

  const long long PS = (long long)HW * NC;  // per-batch stride (elements)
  // f[b][i][o] = xnT · f_w^T  (bias over n=o)
  gemm_nt<<<dim3(32, 4, NB), dim3(256), 0, stream>>>(xnT, PS, NC, wB, 0, NC,
                                                     fB, PS, 0, NC, NC, 0, 0,
                                                     nullptr, f_b, nullptr, 0);
  // g[b][j][o] = ynT · g_w^T
  gemm_nt<<<dim3(32, 4, NB), dim3(256), 0, stream>>>(ynT, PS, NC, wB + 262144, 0, NC,
                                                     gB, PS, 0, NC, NC, 0, 0,
                                                     nullptr, g_b, nullptr, 0);
  // h[b][o][j] = h_w · yT^T  (bias over m=o)
  gemm_nt<<<dim3(4, 32, NB), dim3(256), 0, stream>>>(wB + 524288, 0, NC, yT, PS, NC,
                                                     hB, PS, 0, HW, NC, 0, 0,
                                                     h_b, nullptr, nullptr, 0);

  const int pzs = 31 - __builtin_clz((unsigned)(R * (NC / 4)));  // log2 f32x4 per bg
  for (int b0 = 0; b0 < NB; b0 += G) {
    for (int r0 = 0; r0 < HW; r0 += R) {
      if (R >= 256) {
        // S[bg][i][j] = f[i][:] · g[j][:]  (f32 out) — 256² 2-phase kernel
        gemm_nt2<<<dim3(R / 256, HW / 256, G), dim3(512), 0, stream>>>(
            fB + ((size_t)b0 * HW + r0) * NC, PS, NC,
            gB + (size_t)b0 * PS, PS, NC,
            S, (long long)R * HW, 0, HW, NC, 1, 0, nullptr);
        softmax_k<<<dim3(G * R), dim3(256), 0, stream>>>(S);
        // O partials: split-K=4 into S row tails (4*512 = 2048 f32 exactly)
        gemm_nt2<<<dim3(R / 256, NC / 256, G * 4), dim3(512), 0, stream>>>(
            (const unsigned short*)S, (long long)R * 2 * HW, 2 * HW,
            hB + (size_t)b0 * NC * HW, (long long)NC * HW, HW,
            S + 2048, (long long)R * HW, 512, HW, HW / 4, 1, 2, nullptr);
        reduce_k<<<dim3(G * R / 2), dim3(256), 0, stream>>>(
            S, oB + ((size_t)b0 * HW + r0) * NC, PS, 4, R, pzs);
      } else {
        // tiny-workspace fallback: 128² kernel, split-K=4
        gemm_nt<<<dim3(R / 128, 32, G), dim3(256), 0, stream>>>(
            fB + ((size_t)b0 * HW + r0) * NC, PS, NC,
            gB + (size_t)b0 * PS, PS, NC,
            S, (long long)R * HW, 0, HW, NC, 1, 0, nullptr, nullptr, nullptr, 0);
        softmax_k<<<dim3(G * R), dim3(256), 0, stream>>>(S);
        gemm_nt<<<dim3(R / 128, 4, G * 4), dim3(256), 0, stream>>>(
            (const unsigned short*)S, (long long)R * 2 * HW, 2 * HW,
            hB + (size_t)b0 * NC * HW, (long long)NC * HW, HW,
            S + 2048, (long long)R * HW, 512, HW, HW / 4, 1, 2,
            nullptr, nullptr, nullptr, 0);
        reduce_k<<<dim3(G * R / 2), dim3(256), 0, stream>>>(
            S, oB + ((size_t)b0 * HW + r0) * NC, PS, 4, R, pzs);
      }
    }
  }
  // out[b][o][i] = out_w · O^T + out_b + x   (f32 out)
  gemm_nt<<<dim3(4, 32, NB), dim3(256), 0, stream>>>(wB + 786432, 0, NC, oB, PS, NC,
                                                     out, (long long)NC * HW, 0, HW, NC, 1, 0,
                                                     out_b, nullptr, x, (long long)NC * HW);
}